// Round 1
// baseline (886.667 us; speedup 1.0000x reference)
//
#include <hip/hip_runtime.h>

#define BB 8
#define CC 512
#define NT 1024    // tokens H*W
#define LL 10
#define DQK 64
#define BN_EPS 1e-5f

// ---------------- reduction helpers ----------------
__device__ __forceinline__ float waveSum(float v) {
#pragma unroll
  for (int o = 32; o; o >>= 1) v += __shfl_down(v, o, 64);
  return v;
}
__device__ __forceinline__ float waveMax(float v) {
#pragma unroll
  for (int o = 32; o; o >>= 1) v = fmaxf(v, __shfl_down(v, o, 64));
  return v;
}

// ---------------- hidden means: lm[which][l][b][c] = mean_hw ----------------
__global__ __launch_bounds__(256) void hidden_mean_kernel(
    const float* __restrict__ xh, const float* __restrict__ yh, float* __restrict__ lm) {
  const int LBC = LL * BB * CC;
  int idx = blockIdx.x;  // 0 .. 2*LBC-1
  const float* src = (idx < LBC) ? xh : yh;
  int r = (idx < LBC) ? idx : idx - LBC;
  const float4* p = (const float4*)(src + (size_t)r * NT);
  float4 v = p[threadIdx.x];  // 256 threads * 4 floats = 1024
  float s = v.x + v.y + v.z + v.w;
  s = waveSum(s);
  __shared__ float sb[4];
  int lane = threadIdx.x & 63, wid = threadIdx.x >> 6;
  if (lane == 0) sb[wid] = s;
  __syncthreads();
  if (threadIdx.x == 0) lm[idx] = (sb[0] + sb[1] + sb[2] + sb[3]) * (1.0f / NT);
}

// ---------------- gamma scalars ----------------
__global__ __launch_bounds__(256) void gamma_kernel(
    const float* __restrict__ lm,
    const float* __restrict__ hw1, const float* __restrict__ hw2,
    const float* __restrict__ g1W1, const float* __restrict__ g1b1,
    const float* __restrict__ g1W2, const float* __restrict__ g1b2,
    const float* __restrict__ g2W1, const float* __restrict__ g2b1,
    const float* __restrict__ g2W2, const float* __restrict__ g2b2,
    float* __restrict__ gamma) {
  int which = blockIdx.x >> 3;
  int b = blockIdx.x & 7;
  const float* hw = which ? hw2 : hw1;
  const float* W1 = which ? g2W1 : g1W1;
  const float* b1 = which ? g2b1 : g1b1;
  const float* W2 = which ? g2W2 : g1W2;
  const float* b2 = which ? g2b2 : g1b2;
  __shared__ float sxhw[CC];
  __shared__ float wsm[LL];
  if (threadIdx.x == 0) {
    float mx = -1e30f;
    for (int l = 0; l < LL; l++) mx = fmaxf(mx, hw[l]);
    float den = 0.f, e[LL];
    for (int l = 0; l < LL; l++) { e[l] = __expf(hw[l] - mx); den += e[l]; }
    for (int l = 0; l < LL; l++) wsm[l] = e[l] / den;
  }
  __syncthreads();
  const float* lmb = lm + (size_t)which * LL * BB * CC + b * CC;
  for (int c = threadIdx.x; c < CC; c += blockDim.x) {
    float a = 0.f;
    for (int l = 0; l < LL; l++) a += wsm[l] * lmb[l * BB * CC + c];
    sxhw[c] = a;
  }
  __syncthreads();
  float contrib = 0.f;
  if (threadIdx.x < 64) {
    int d = threadIdx.x;
    float a = b1[d];
    const float* wr = W1 + d * CC;
    for (int c = 0; c < CC; c++) a = fmaf(wr[c], sxhw[c], a);
    contrib = W2[d] * fmaxf(a, 0.f);
  }
  contrib = waveSum(contrib);
  if (threadIdx.x == 0) gamma[which * BB + b] = contrib + b2[0];
}

// ---------------- generic inner-product macro ----------------
#define GEMM_INNER(AS, BS)                                                         \
  _Pragma("unroll")                                                                \
  for (int kk = 0; kk < 16; kk++) {                                                \
    const float4 a4 = *(const float4*)&AS[kk][ty * 4];                             \
    const float4 b4 = *(const float4*)&BS[kk][tx * 4];                             \
    acc0.x = fmaf(a4.x, b4.x, acc0.x); acc0.y = fmaf(a4.x, b4.y, acc0.y);          \
    acc0.z = fmaf(a4.x, b4.z, acc0.z); acc0.w = fmaf(a4.x, b4.w, acc0.w);          \
    acc1.x = fmaf(a4.y, b4.x, acc1.x); acc1.y = fmaf(a4.y, b4.y, acc1.y);          \
    acc1.z = fmaf(a4.y, b4.z, acc1.z); acc1.w = fmaf(a4.y, b4.w, acc1.w);          \
    acc2.x = fmaf(a4.z, b4.x, acc2.x); acc2.y = fmaf(a4.z, b4.y, acc2.y);          \
    acc2.z = fmaf(a4.z, b4.z, acc2.z); acc2.w = fmaf(a4.z, b4.w, acc2.w);          \
    acc3.x = fmaf(a4.w, b4.x, acc3.x); acc3.y = fmaf(a4.w, b4.y, acc3.y);          \
    acc3.z = fmaf(a4.w, b4.z, acc3.z); acc3.w = fmaf(a4.w, b4.w, acc3.w);          \
  }

// C[b][m][n] = (sum_k A[m][k]*B[b][k][n] + bias[m]) * (scale?scale[b]:1)
__global__ __launch_bounds__(256) void gemm_nn_kernel(
    const float* __restrict__ A, long long sA,
    const float* __restrict__ Bm, long long sB,
    float* __restrict__ Cm, long long sC,
    int K, const float* __restrict__ bias, const float* __restrict__ scale) {
  __shared__ float As[16][68];
  __shared__ float Bs[16][68];
  const int b = blockIdx.z;
  const int m0 = blockIdx.y * 64, n0 = blockIdx.x * 64;
  const float* Ab = A + (size_t)b * sA;
  const float* Bb = Bm + (size_t)b * sB;
  const int tid = threadIdx.x;
  const int tx = tid & 15, ty = tid >> 4;
  const int ka = tid & 15, ma = tid >> 4;
  const int nb = tid & 63, kb = tid >> 6;
  float4 acc0 = {0,0,0,0}, acc1 = {0,0,0,0}, acc2 = {0,0,0,0}, acc3 = {0,0,0,0};
  for (int k0 = 0; k0 < K; k0 += 16) {
#pragma unroll
    for (int t = 0; t < 4; t++)
      As[ka][ma + t * 16] = Ab[(size_t)(m0 + ma + t * 16) * K + (k0 + ka)];
#pragma unroll
    for (int t = 0; t < 4; t++)
      Bs[kb + t * 4][nb] = Bb[(size_t)(k0 + kb + t * 4) * NT + (n0 + nb)];
    __syncthreads();
    GEMM_INNER(As, Bs)
    __syncthreads();
  }
  const float sc = scale ? scale[b] : 1.0f;
  float* Cb = Cm + (size_t)b * sC;
#define STORE_ROW(i, A4) {                                              \
    int m = m0 + ty * 4 + i;                                            \
    float bi = bias ? bias[m] : 0.0f;                                   \
    float4 r = A4;                                                      \
    r.x = (r.x + bi) * sc; r.y = (r.y + bi) * sc;                       \
    r.z = (r.z + bi) * sc; r.w = (r.w + bi) * sc;                       \
    *(float4*)&Cb[(size_t)m * NT + n0 + tx * 4] = r; }
  STORE_ROW(0, acc0) STORE_ROW(1, acc1) STORE_ROW(2, acc2) STORE_ROW(3, acc3)
#undef STORE_ROW
}

// S[b][n][m] = sum_d Q[b][d][n] * K[b][d][m]   (scores, K-dim = DQK)
__global__ __launch_bounds__(256) void gemm_tn_kernel(
    const float* __restrict__ Q, const float* __restrict__ Kp, float* __restrict__ S) {
  __shared__ float Qs[16][68];
  __shared__ float Ks[16][68];
  const int b = blockIdx.z;
  const int n0 = blockIdx.y * 64, m0 = blockIdx.x * 64;
  const float* Qb = Q + (size_t)b * DQK * NT;
  const float* Kb = Kp + (size_t)b * DQK * NT;
  const int tid = threadIdx.x;
  const int tx = tid & 15, ty = tid >> 4;
  const int cl = tid & 63, kl = tid >> 6;
  float4 acc0 = {0,0,0,0}, acc1 = {0,0,0,0}, acc2 = {0,0,0,0}, acc3 = {0,0,0,0};
  for (int k0 = 0; k0 < DQK; k0 += 16) {
#pragma unroll
    for (int t = 0; t < 4; t++) {
      Qs[kl + t * 4][cl] = Qb[(size_t)(k0 + kl + t * 4) * NT + n0 + cl];
      Ks[kl + t * 4][cl] = Kb[(size_t)(k0 + kl + t * 4) * NT + m0 + cl];
    }
    __syncthreads();
    GEMM_INNER(Qs, Ks)
    __syncthreads();
  }
  float* Sb = S + (size_t)b * NT * NT;
#define STORE_ROW(i, A4) {                                              \
    int n = n0 + ty * 4 + i;                                            \
    *(float4*)&Sb[(size_t)n * NT + m0 + tx * 4] = A4; }
  STORE_ROW(0, acc0) STORE_ROW(1, acc1) STORE_ROW(2, acc2) STORE_ROW(3, acc3)
#undef STORE_ROW
}

// C[b][c][m] = scale[b] * sum_n V[b][c][n] * At[b][m][n]   (out1 = V @ attn^T)
__global__ __launch_bounds__(256) void gemm_nt_kernel(
    const float* __restrict__ V, const float* __restrict__ At, float* __restrict__ Cm,
    const float* __restrict__ scale) {
  __shared__ float As[16][68];
  __shared__ float Bs[16][68];
  const int b = blockIdx.z;
  const int c0 = blockIdx.y * 64, n0 = blockIdx.x * 64;
  const float* Vb = V + (size_t)b * CC * NT;
  const float* Ab = At + (size_t)b * NT * NT;
  const int tid = threadIdx.x;
  const int tx = tid & 15, ty = tid >> 4;
  const int ka = tid & 15, ma = tid >> 4;
  float4 acc0 = {0,0,0,0}, acc1 = {0,0,0,0}, acc2 = {0,0,0,0}, acc3 = {0,0,0,0};
  for (int k0 = 0; k0 < NT; k0 += 16) {
#pragma unroll
    for (int t = 0; t < 4; t++) {
      As[ka][ma + t * 16] = Vb[(size_t)(c0 + ma + t * 16) * NT + k0 + ka];
      Bs[ka][ma + t * 16] = Ab[(size_t)(n0 + ma + t * 16) * NT + k0 + ka];
    }
    __syncthreads();
    GEMM_INNER(As, Bs)
    __syncthreads();
  }
  const float sc = scale[b];
  float* Cb = Cm + (size_t)b * CC * NT;
#define STORE_ROW(i, A4) {                                              \
    int c = c0 + ty * 4 + i;                                            \
    float4 r = A4;                                                      \
    r.x *= sc; r.y *= sc; r.z *= sc; r.w *= sc;                         \
    *(float4*)&Cb[(size_t)c * NT + n0 + tx * 4] = r; }
  STORE_ROW(0, acc0) STORE_ROW(1, acc1) STORE_ROW(2, acc2) STORE_ROW(3, acc3)
#undef STORE_ROW
}

// ---------------- row softmax (in place), one block per row ----------------
__global__ __launch_bounds__(256) void softmax_kernel(float* __restrict__ S) {
  float4* row = (float4*)(S + (size_t)blockIdx.x * NT);
  float4 v = row[threadIdx.x];
  __shared__ float sb[4];
  __shared__ float broad;
  int lane = threadIdx.x & 63, wid = threadIdx.x >> 6;
  float mx = fmaxf(fmaxf(v.x, v.y), fmaxf(v.z, v.w));
  mx = waveMax(mx);
  if (lane == 0) sb[wid] = mx;
  __syncthreads();
  if (threadIdx.x == 0) broad = fmaxf(fmaxf(sb[0], sb[1]), fmaxf(sb[2], sb[3]));
  __syncthreads();
  mx = broad;
  v.x = __expf(v.x - mx); v.y = __expf(v.y - mx);
  v.z = __expf(v.z - mx); v.w = __expf(v.w - mx);
  float s = v.x + v.y + v.z + v.w;
  s = waveSum(s);
  __syncthreads();  // protect sb reuse
  if (lane == 0) sb[wid] = s;
  __syncthreads();
  if (threadIdx.x == 0) broad = sb[0] + sb[1] + sb[2] + sb[3];
  __syncthreads();
  float inv = 1.0f / broad;
  v.x *= inv; v.y *= inv; v.z *= inv; v.w *= inv;
  row[threadIdx.x] = v;
}

// ---------------- BN stats: one block per channel ----------------
__global__ __launch_bounds__(256) void bnstats_kernel(
    const float* __restrict__ Z, const float* __restrict__ g, const float* __restrict__ bet,
    float* __restrict__ scale, float* __restrict__ shift) {
  int c = blockIdx.x;
  float s = 0.f, s2 = 0.f;
  for (int b = 0; b < BB; b++) {
    const float4* p = (const float4*)(Z + ((size_t)b * CC + c) * NT);
    float4 v = p[threadIdx.x];
    s += v.x + v.y + v.z + v.w;
    s2 += v.x * v.x + v.y * v.y + v.z * v.z + v.w * v.w;
  }
  s = waveSum(s); s2 = waveSum(s2);
  __shared__ float sb[8];
  int lane = threadIdx.x & 63, wid = threadIdx.x >> 6;
  if (lane == 0) { sb[wid] = s; sb[wid + 4] = s2; }
  __syncthreads();
  if (threadIdx.x == 0) {
    float S = sb[0] + sb[1] + sb[2] + sb[3];
    float S2 = sb[4] + sb[5] + sb[6] + sb[7];
    const float invn = 1.0f / (BB * NT);
    float mean = S * invn;
    float var = S2 * invn - mean * mean;
    float inv = rsqrtf(var + BN_EPS);
    float sc = g[c] * inv;
    scale[c] = sc;
    shift[c] = bet[c] - mean * sc;
  }
}

// z = relu(z*scale[c] + shift[c]) in place
__global__ __launch_bounds__(256) void bn_apply_relu_kernel(
    float* __restrict__ Z, const float* __restrict__ scale, const float* __restrict__ shift) {
  size_t i4 = (size_t)blockIdx.x * blockDim.x + threadIdx.x;
  int c = (int)((i4 >> 8) & (CC - 1));
  float4 v = ((float4*)Z)[i4];
  float sc = scale[c], sh = shift[c];
  v.x = fmaxf(fmaf(v.x, sc, sh), 0.f); v.y = fmaxf(fmaf(v.y, sc, sh), 0.f);
  v.z = fmaxf(fmaf(v.z, sc, sh), 0.f); v.w = fmaxf(fmaf(v.w, sc, sh), 0.f);
  ((float4*)Z)[i4] = v;
}

// out = relu(z*scale[c] + shift[c] + x)
__global__ __launch_bounds__(256) void bn_final_kernel(
    const float* __restrict__ Z, const float* __restrict__ X,
    const float* __restrict__ scale, const float* __restrict__ shift,
    float* __restrict__ Out) {
  size_t i4 = (size_t)blockIdx.x * blockDim.x + threadIdx.x;
  int c = (int)((i4 >> 8) & (CC - 1));
  float4 v = ((const float4*)Z)[i4];
  float4 x = ((const float4*)X)[i4];
  float sc = scale[c], sh = shift[c];
  v.x = fmaxf(fmaf(v.x, sc, sh) + x.x, 0.f); v.y = fmaxf(fmaf(v.y, sc, sh) + x.y, 0.f);
  v.z = fmaxf(fmaf(v.z, sc, sh) + x.z, 0.f); v.w = fmaxf(fmaf(v.w, sc, sh) + x.w, 0.f);
  ((float4*)Out)[i4] = v;
}

extern "C" void kernel_launch(void* const* d_in, const int* in_sizes, int n_in,
                              void* d_out, int out_size, void* d_ws, size_t ws_size,
                              hipStream_t stream) {
  (void)in_sizes; (void)n_in; (void)out_size; (void)ws_size;
  const float* x    = (const float*)d_in[0];
  const float* y    = (const float*)d_in[1];
  const float* xh   = (const float*)d_in[2];
  const float* yh   = (const float*)d_in[3];
  const float* qW   = (const float*)d_in[4];
  const float* qb   = (const float*)d_in[5];
  const float* kW   = (const float*)d_in[6];
  const float* kb   = (const float*)d_in[7];
  const float* v1W  = (const float*)d_in[8];
  const float* v1b  = (const float*)d_in[9];
  const float* v2W  = (const float*)d_in[10];
  const float* v2b  = (const float*)d_in[11];
  const float* hw1  = (const float*)d_in[12];
  const float* hw2  = (const float*)d_in[13];
  const float* g1W1 = (const float*)d_in[14];
  const float* g1b1 = (const float*)d_in[15];
  const float* g1W2 = (const float*)d_in[16];
  const float* g1b2 = (const float*)d_in[17];
  const float* g2W1 = (const float*)d_in[18];
  const float* g2b1 = (const float*)d_in[19];
  const float* g2W2 = (const float*)d_in[20];
  const float* g2b2 = (const float*)d_in[21];
  const float* rW1  = (const float*)d_in[22];
  // d_in[23] = rb1: dropped (BatchNorm removes constant per-channel bias)
  const float* bn1g = (const float*)d_in[24];
  const float* bn1b = (const float*)d_in[25];
  const float* rW2  = (const float*)d_in[26];
  // d_in[27] = rb2: dropped
  const float* bn2g = (const float*)d_in[28];
  const float* bn2b = (const float*)d_in[29];
  float* out = (float*)d_out;

  // workspace layout (floats)
  float* ws   = (float*)d_ws;
  float* lm   = ws;                                 // 2*LL*BB*CC = 81920
  float* gam  = lm + 2 * LL * BB * CC;              // 16
  float* scA  = gam + 16;                           // 512
  float* shA  = scA + CC;                           // 512
  float* qb_  = shA + CC;                           // BB*DQK*NT = 524288
  float* kb_  = qb_ + (size_t)BB * DQK * NT;        // 524288
  float* v1_  = kb_ + (size_t)BB * DQK * NT;        // 4194304
  float* v2_  = v1_ + (size_t)BB * CC * NT;         // 4194304
  float* attn = v2_ + (size_t)BB * CC * NT;         // 8388608
  float* t1   = attn + (size_t)BB * NT * NT;        // 4194304
  float* t2   = t1 + (size_t)BB * CC * NT;          // 4194304
  float* z0   = t2 + (size_t)BB * CC * NT;          // 4194304
  float* z2a  = v1_;  // reuse after v1 consumed
  float* z2b  = v2_;  // reuse after v2 consumed

  const long long sX = (long long)CC * NT;   // batch stride of x/y/v/t/z
  const long long sQ = (long long)DQK * NT;
  const long long sS = (long long)NT * NT;

  // 1) hidden means + gamma
  hidden_mean_kernel<<<2 * LL * BB * CC, 256, 0, stream>>>(xh, yh, lm);
  gamma_kernel<<<16, 256, 0, stream>>>(lm, hw1, hw2, g1W1, g1b1, g1W2, g1b2,
                                       g2W1, g2b1, g2W2, g2b2, gam);

  // 2) projections
  gemm_nn_kernel<<<dim3(16, 1, 8), 256, 0, stream>>>(qW, 0, x, sX, qb_, sQ, CC, qb, nullptr);
  gemm_nn_kernel<<<dim3(16, 1, 8), 256, 0, stream>>>(kW, 0, y, sX, kb_, sQ, CC, kb, nullptr);
  gemm_nn_kernel<<<dim3(16, 8, 8), 256, 0, stream>>>(v1W, 0, x, sX, v1_, sX, CC, v1b, nullptr);
  gemm_nn_kernel<<<dim3(16, 8, 8), 256, 0, stream>>>(v2W, 0, y, sX, v2_, sX, CC, v2b, nullptr);

  // 3) attention
  gemm_tn_kernel<<<dim3(16, 16, 8), 256, 0, stream>>>(qb_, kb_, attn);
  softmax_kernel<<<BB * NT, 256, 0, stream>>>(attn);
  gemm_nt_kernel<<<dim3(16, 8, 8), 256, 0, stream>>>(v1_, attn, t1, gam + 0);        // gamma1*out1
  gemm_nn_kernel<<<dim3(16, 8, 8), 256, 0, stream>>>(v2_, sX, attn, sS, t2, sX, NT,
                                                     nullptr, gam + BB);             // gamma2*out2

  // 4) residual chain 1 (input t1, skip x) -> out[0..]
  gemm_nn_kernel<<<dim3(16, 8, 8), 256, 0, stream>>>(rW1, 0, t1, sX, z0, sX, CC, nullptr, nullptr);
  bnstats_kernel<<<CC, 256, 0, stream>>>(z0, bn1g, bn1b, scA, shA);
  bn_apply_relu_kernel<<<4096, 256, 0, stream>>>(z0, scA, shA);
  gemm_nn_kernel<<<dim3(16, 8, 8), 256, 0, stream>>>(rW2, 0, z0, sX, z2a, sX, CC, nullptr, nullptr);
  bnstats_kernel<<<CC, 256, 0, stream>>>(z2a, bn2g, bn2b, scA, shA);
  bn_final_kernel<<<4096, 256, 0, stream>>>(z2a, x, scA, shA, out);

  // 5) residual chain 2 (input t2, skip y) -> out[BB*CC*NT..]
  gemm_nn_kernel<<<dim3(16, 8, 8), 256, 0, stream>>>(rW1, 0, t2, sX, z0, sX, CC, nullptr, nullptr);
  bnstats_kernel<<<CC, 256, 0, stream>>>(z0, bn1g, bn1b, scA, shA);
  bn_apply_relu_kernel<<<4096, 256, 0, stream>>>(z0, scA, shA);
  gemm_nn_kernel<<<dim3(16, 8, 8), 256, 0, stream>>>(rW2, 0, z0, sX, z2b, sX, CC, nullptr, nullptr);
  bnstats_kernel<<<CC, 256, 0, stream>>>(z2b, bn2g, bn2b, scA, shA);
  bn_final_kernel<<<4096, 256, 0, stream>>>(z2b, y, scA, shA, out + (size_t)BB * CC * NT);
}

// Round 3
// 450.316 us; speedup vs baseline: 1.9690x; 1.9690x over previous
//
#include <hip/hip_runtime.h>

#define BB 8
#define CC 512
#define NT 1024
#define LL 10
#define DQK 64
#define BN_EPS 1e-5f

using u16 = unsigned short;
typedef __attribute__((ext_vector_type(8))) short short8;
typedef __attribute__((ext_vector_type(4))) float f32x4;

// ---------------- helpers ----------------
__device__ __forceinline__ float waveSum(float v) {
#pragma unroll
  for (int o = 32; o; o >>= 1) v += __shfl_down(v, o, 64);
  return v;
}
__device__ __forceinline__ float waveMax(float v) {
#pragma unroll
  for (int o = 32; o; o >>= 1) v = fmaxf(v, __shfl_down(v, o, 64));
  return v;
}
__device__ __forceinline__ u16 f2bf(float f) {
  unsigned u = __float_as_uint(f);
  u += 0x7FFFu + ((u >> 16) & 1u);
  return (u16)(u >> 16);
}
__device__ __forceinline__ float bf2f(u16 h) {
  return __uint_as_float(((unsigned)h) << 16);
}
// async global->LDS, 16B/lane; LDS dest must be wave-uniform base + lane*16
__device__ __forceinline__ void g2l16(const u16* g, void* l) {
  __builtin_amdgcn_global_load_lds(
      (const __attribute__((address_space(1))) unsigned int*)g,
      (__attribute__((address_space(3))) unsigned int*)l, 16, 0, 0);
}

// ---------------- hidden means ----------------
__global__ __launch_bounds__(256) void hidden_mean_kernel(
    const float* __restrict__ xh, const float* __restrict__ yh, float* __restrict__ lm) {
  const int LBC = LL * BB * CC;
  int idx = blockIdx.x;
  const float* src = (idx < LBC) ? xh : yh;
  int r = (idx < LBC) ? idx : idx - LBC;
  const float4* p = (const float4*)(src + (size_t)r * NT);
  float4 v = p[threadIdx.x];
  float s = v.x + v.y + v.z + v.w;
  s = waveSum(s);
  __shared__ float sb[4];
  int lane = threadIdx.x & 63, wid = threadIdx.x >> 6;
  if (lane == 0) sb[wid] = s;
  __syncthreads();
  if (threadIdx.x == 0) lm[idx] = (sb[0] + sb[1] + sb[2] + sb[3]) * (1.0f / NT);
}

// ---------------- gamma scalars ----------------
__global__ __launch_bounds__(256) void gamma_kernel(
    const float* __restrict__ lm,
    const float* __restrict__ hw1, const float* __restrict__ hw2,
    const float* __restrict__ g1W1, const float* __restrict__ g1b1,
    const float* __restrict__ g1W2, const float* __restrict__ g1b2,
    const float* __restrict__ g2W1, const float* __restrict__ g2b1,
    const float* __restrict__ g2W2, const float* __restrict__ g2b2,
    float* __restrict__ gamma) {
  int which = blockIdx.x >> 3;
  int b = blockIdx.x & 7;
  const float* hw = which ? hw2 : hw1;
  const float* W1 = which ? g2W1 : g1W1;
  const float* b1 = which ? g2b1 : g1b1;
  const float* W2 = which ? g2W2 : g1W2;
  const float* b2 = which ? g2b2 : g1b2;
  __shared__ float sxhw[CC];
  __shared__ float wsm[LL];
  if (threadIdx.x == 0) {
    float mx = -1e30f;
    for (int l = 0; l < LL; l++) mx = fmaxf(mx, hw[l]);
    float den = 0.f, e[LL];
    for (int l = 0; l < LL; l++) { e[l] = __expf(hw[l] - mx); den += e[l]; }
    for (int l = 0; l < LL; l++) wsm[l] = e[l] / den;
  }
  __syncthreads();
  const float* lmb = lm + (size_t)which * LL * BB * CC + b * CC;
  for (int c = threadIdx.x; c < CC; c += blockDim.x) {
    float a = 0.f;
    for (int l = 0; l < LL; l++) a += wsm[l] * lmb[l * BB * CC + c];
    sxhw[c] = a;
  }
  __syncthreads();
  float contrib = 0.f;
  if (threadIdx.x < 64) {
    int d = threadIdx.x;
    float a = b1[d];
    const float* wr = W1 + d * CC;
    for (int c = 0; c < CC; c++) a = fmaf(wr[c], sxhw[c], a);
    contrib = W2[d] * fmaxf(a, 0.f);
  }
  contrib = waveSum(contrib);
  if (threadIdx.x == 0) gamma[which * BB + b] = contrib + b2[0];
}

// ---------------- weights fp32 -> bf16 (hi only), 4 segments ----------------
struct WcvtArgs {
  const float* src[4];
  int nblk[5];
};
__global__ __launch_bounds__(256) void wcvt_kernel(WcvtArgs a, u16* __restrict__ dst) {
  int blk = blockIdx.x;
  int seg = 0;
  while (blk >= a.nblk[seg + 1]) seg++;
  int rel = blk - a.nblk[seg];
  const float4* s4 = (const float4*)a.src[seg];
  float4 v = s4[(size_t)rel * 256 + threadIdx.x];
  uint2 o;
  o.x = (unsigned)f2bf(v.x) | ((unsigned)f2bf(v.y) << 16);
  o.y = (unsigned)f2bf(v.z) | ((unsigned)f2bf(v.w) << 16);
  ((uint2*)dst)[(size_t)blk * 256 + threadIdx.x] = o;
}

// ---------------- qW/kW fp32 -> split (hi, lo) bf16 ----------------
__global__ __launch_bounds__(256) void wcvt_split_kernel(
    const float* __restrict__ qW, const float* __restrict__ kW,
    u16* __restrict__ qh, u16* __restrict__ ql,
    u16* __restrict__ kh, u16* __restrict__ kl) {
  int blk = blockIdx.x;  // 64 blocks of 1024 elems; 0..31 qW, 32..63 kW
  const float* src = (blk < 32) ? qW : kW;
  u16* dh = (blk < 32) ? qh : kh;
  u16* dl = (blk < 32) ? ql : kl;
  int rel = blk & 31;
  float4 v = ((const float4*)src)[(size_t)rel * 256 + threadIdx.x];
  u16 h0 = f2bf(v.x), h1 = f2bf(v.y), h2 = f2bf(v.z), h3 = f2bf(v.w);
  u16 l0 = f2bf(v.x - bf2f(h0)), l1 = f2bf(v.y - bf2f(h1));
  u16 l2 = f2bf(v.z - bf2f(h2)), l3 = f2bf(v.w - bf2f(h3));
  uint2 oh, ol;
  oh.x = (unsigned)h0 | ((unsigned)h1 << 16); oh.y = (unsigned)h2 | ((unsigned)h3 << 16);
  ol.x = (unsigned)l0 | ((unsigned)l1 << 16); ol.y = (unsigned)l2 | ((unsigned)l3 << 16);
  ((uint2*)dh)[(size_t)rel * 256 + threadIdx.x] = oh;
  ((uint2*)dl)[(size_t)rel * 256 + threadIdx.x] = ol;
}

// ---------------- x/y [B][C][N] fp32 -> token-major split bf16 ----------------
__global__ __launch_bounds__(256) void transpose_xy_kernel(
    const float* __restrict__ x, const float* __restrict__ y,
    u16* __restrict__ xth, u16* __restrict__ xtl,
    u16* __restrict__ yth, u16* __restrict__ ytl) {
  __shared__ float t[64][65];
  int z = blockIdx.z;
  const float* src = (z < 8) ? x : y;
  u16* dh = (z < 8) ? xth : yth;
  u16* dl = (z < 8) ? xtl : ytl;
  int b = z & 7;
  int n0 = blockIdx.x * 64, c0 = blockIdx.y * 64;
  int tc = threadIdx.x & 63, tr = threadIdx.x >> 6;
  const float* S = src + ((size_t)b * CC + c0) * NT + n0;
#pragma unroll
  for (int r = 0; r < 16; r++) {
    int c = tr + r * 4;
    t[c][tc] = S[(size_t)c * NT + tc];
  }
  __syncthreads();
  size_t base = ((size_t)b * NT + n0) * CC + c0;
#pragma unroll
  for (int r = 0; r < 16; r++) {
    int n = tr + r * 4;
    float v = t[tc][n];
    u16 h = f2bf(v);
    dh[base + (size_t)n * CC + tc] = h;
    dl[base + (size_t)n * CC + tc] = f2bf(v - bf2f(h));
  }
}

// ---------------- attn [b][n][m] bf16 -> attnT [b][m][n] bf16 ----------------
__global__ __launch_bounds__(256) void transpose_attn_kernel(
    const u16* __restrict__ attn, u16* __restrict__ attnT) {
  __shared__ u16 t[64][66];
  int b = blockIdx.z;
  int n0 = blockIdx.y * 64, m0 = blockIdx.x * 64;
  int tc = threadIdx.x & 63, tr = threadIdx.x >> 6;
  const u16* S = attn + ((size_t)b * NT + n0) * NT + m0;
#pragma unroll
  for (int r = 0; r < 16; r++) {
    int nr = tr + r * 4;
    t[nr][tc] = S[(size_t)nr * NT + tc];
  }
  __syncthreads();
  u16* D = attnT + ((size_t)b * NT + m0) * NT + n0;
#pragma unroll
  for (int r = 0; r < 16; r++) {
    int mr = tr + r * 4;
    D[(size_t)mr * NT + tc] = t[tc][mr];
  }
}

// ---------------- bf16 MFMA GEMM: Out[i][j] = (sum_k A[i][k]*B[j][k] + biases)*scale ----------------
template <int BN>
__global__ __launch_bounds__(256) void gemm_bf16(
    const u16* __restrict__ A, long long sA, int lda,
    const u16* __restrict__ B, long long sB, int ldb,
    void* __restrict__ C, long long sC, int ldc,
    int K, int storef32,
    const float* __restrict__ bias_row, const float* __restrict__ bias_col,
    const float* __restrict__ scale) {
  constexpr int BM = 128, BK = 32;
  constexpr int WN = (BN == 128) ? 2 : 1;
  constexpr int WM = 4 / WN;
  constexpr int FM = BM / (WM * 16);
  constexpr int FN = BN / (WN * 16);
  __shared__ u16 As[BM * BK];
  __shared__ u16 Bs[BN * BK];
  const int bz = blockIdx.z;
  const int i0 = blockIdx.y * BM;
  const int j0 = blockIdx.x * BN;
  const u16* Ab = A + (size_t)bz * sA + (size_t)i0 * lda;
  const u16* Bb = B + (size_t)bz * sB + (size_t)j0 * ldb;
  const int tid = threadIdx.x;
  const int lane = tid & 63;
  const int wave = tid >> 6;
  const int wr = wave / WN, wc = wave % WN;
  const int fr = lane & 15;
  const int kg = lane >> 4;
  const int arow = tid >> 2;
  const int aq = tid & 3;

  f32x4 acc[FM][FN] = {};

  for (int k0 = 0; k0 < K; k0 += BK) {
#pragma unroll
    for (int c = 0; c < (BM * BK * 2) / 4096; c++)
      g2l16(Ab + (size_t)(arow + c * 64) * lda + k0 + aq * 8,
            (char*)As + c * 4096 + tid * 16);
#pragma unroll
    for (int c = 0; c < (BN * BK * 2) / 4096; c++)
      g2l16(Bb + (size_t)(arow + c * 64) * ldb + k0 + aq * 8,
            (char*)Bs + c * 4096 + tid * 16);
    __syncthreads();
    short8 fa[FM], fb[FN];
#pragma unroll
    for (int i = 0; i < FM; i++)
      fa[i] = *(const short8*)&As[(wr * FM * 16 + i * 16 + fr) * BK + kg * 8];
#pragma unroll
    for (int j = 0; j < FN; j++)
      fb[j] = *(const short8*)&Bs[(wc * FN * 16 + j * 16 + fr) * BK + kg * 8];
#pragma unroll
    for (int i = 0; i < FM; i++)
#pragma unroll
      for (int j = 0; j < FN; j++)
        acc[i][j] = __builtin_amdgcn_mfma_f32_16x16x32_bf16(fa[i], fb[j], acc[i][j], 0, 0, 0);
    __syncthreads();
  }

  const float scl = scale ? scale[bz] : 1.0f;
  float* Cf = (float*)C + (size_t)bz * sC;
  u16* Ch = (u16*)C + (size_t)bz * sC;
#pragma unroll
  for (int i = 0; i < FM; i++) {
#pragma unroll
    for (int j = 0; j < FN; j++) {
      int col = j0 + wc * FN * 16 + j * 16 + fr;
      float cb = bias_col ? bias_col[col] : 0.0f;
#pragma unroll
      for (int r = 0; r < 4; r++) {
        int row = i0 + wr * FM * 16 + i * 16 + kg * 4 + r;
        float rb = bias_row ? bias_row[row] : 0.0f;
        float v = (acc[i][j][r] + cb + rb) * scl;
        if (storef32) Cf[(size_t)row * ldc + col] = v;
        else Ch[(size_t)row * ldc + col] = f2bf(v);
      }
    }
  }
}

// ---------------- split-bf16 GEMM (~fp32 accuracy): Out = A*B^T with A,B = hi+lo ----------------
// BM=128, BN=64, 4 waves along M. Out: fp32 (Cf) or split bf16 pair (Ch,Cl).
__global__ __launch_bounds__(256) void gemm_split(
    const u16* __restrict__ Ah_, const u16* __restrict__ Al_, long long sA, int lda,
    const u16* __restrict__ Bh_, const u16* __restrict__ Bl_, long long sB, int ldb,
    float* __restrict__ Cf, u16* __restrict__ Ch, u16* __restrict__ Cl,
    long long sC, int ldc, int K, const float* __restrict__ bias_col) {
  constexpr int BM = 128, BN = 64, BK = 32;
  constexpr int FM = 2, FN = 4;
  __shared__ u16 Ahs[BM * BK];
  __shared__ u16 Als[BM * BK];
  __shared__ u16 Bhs[BN * BK];
  __shared__ u16 Bls[BN * BK];
  const int bz = blockIdx.z;
  const int i0 = blockIdx.y * BM;
  const int j0 = blockIdx.x * BN;
  const u16* Abh = Ah_ + (size_t)bz * sA + (size_t)i0 * lda;
  const u16* Abl = Al_ + (size_t)bz * sA + (size_t)i0 * lda;
  const u16* Bbh = Bh_ + (size_t)bz * sB + (size_t)j0 * ldb;
  const u16* Bbl = Bl_ + (size_t)bz * sB + (size_t)j0 * ldb;
  const int tid = threadIdx.x;
  const int lane = tid & 63;
  const int wr = tid >> 6;   // wave = M-slot
  const int fr = lane & 15;
  const int kg = lane >> 4;
  const int arow = tid >> 2;
  const int aq = tid & 3;

  f32x4 acc[FM][FN] = {};

  for (int k0 = 0; k0 < K; k0 += BK) {
#pragma unroll
    for (int c = 0; c < 2; c++) {
      g2l16(Abh + (size_t)(arow + c * 64) * lda + k0 + aq * 8,
            (char*)Ahs + c * 4096 + tid * 16);
      g2l16(Abl + (size_t)(arow + c * 64) * lda + k0 + aq * 8,
            (char*)Als + c * 4096 + tid * 16);
    }
    g2l16(Bbh + (size_t)arow * ldb + k0 + aq * 8, (char*)Bhs + tid * 16);
    g2l16(Bbl + (size_t)arow * ldb + k0 + aq * 8, (char*)Bls + tid * 16);
    __syncthreads();
    short8 fah[FM], fal[FM], fbh[FN], fbl[FN];
#pragma unroll
    for (int i = 0; i < FM; i++) {
      fah[i] = *(const short8*)&Ahs[(wr * 32 + i * 16 + fr) * BK + kg * 8];
      fal[i] = *(const short8*)&Als[(wr * 32 + i * 16 + fr) * BK + kg * 8];
    }
#pragma unroll
    for (int j = 0; j < FN; j++) {
      fbh[j] = *(const short8*)&Bhs[(j * 16 + fr) * BK + kg * 8];
      fbl[j] = *(const short8*)&Bls[(j * 16 + fr) * BK + kg * 8];
    }
#pragma unroll
    for (int i = 0; i < FM; i++)
#pragma unroll
      for (int j = 0; j < FN; j++) {
        acc[i][j] = __builtin_amdgcn_mfma_f32_16x16x32_bf16(fah[i], fbh[j], acc[i][j], 0, 0, 0);
        acc[i][j] = __builtin_amdgcn_mfma_f32_16x16x32_bf16(fah[i], fbl[j], acc[i][j], 0, 0, 0);
        acc[i][j] = __builtin_amdgcn_mfma_f32_16x16x32_bf16(fal[i], fbh[j], acc[i][j], 0, 0, 0);
      }
    __syncthreads();
  }

  float* Cfb = Cf ? Cf + (size_t)bz * sC : nullptr;
  u16* Chb = Ch ? Ch + (size_t)bz * sC : nullptr;
  u16* Clb = Cl ? Cl + (size_t)bz * sC : nullptr;
#pragma unroll
  for (int i = 0; i < FM; i++) {
#pragma unroll
    for (int j = 0; j < FN; j++) {
      int col = j0 + j * 16 + fr;
      float cb = bias_col ? bias_col[col] : 0.0f;
#pragma unroll
      for (int r = 0; r < 4; r++) {
        int row = i0 + wr * 32 + i * 16 + kg * 4 + r;
        float v = acc[i][j][r] + cb;
        if (Cfb) {
          Cfb[(size_t)row * ldc + col] = v;
        } else {
          u16 h = f2bf(v);
          Chb[(size_t)row * ldc + col] = h;
          Clb[(size_t)row * ldc + col] = f2bf(v - bf2f(h));
        }
      }
    }
  }
}

// ---------------- softmax: S fp32 row -> attn bf16 row ----------------
__global__ __launch_bounds__(256) void softmax_bf_kernel(
    const float* __restrict__ S, u16* __restrict__ A) {
  const float4* row = (const float4*)(S + (size_t)blockIdx.x * NT);
  float4 v = row[threadIdx.x];
  __shared__ float sb[4];
  __shared__ float broad;
  int lane = threadIdx.x & 63, wid = threadIdx.x >> 6;
  float mx = fmaxf(fmaxf(v.x, v.y), fmaxf(v.z, v.w));
  mx = waveMax(mx);
  if (lane == 0) sb[wid] = mx;
  __syncthreads();
  if (threadIdx.x == 0) broad = fmaxf(fmaxf(sb[0], sb[1]), fmaxf(sb[2], sb[3]));
  __syncthreads();
  mx = broad;
  v.x = __expf(v.x - mx); v.y = __expf(v.y - mx);
  v.z = __expf(v.z - mx); v.w = __expf(v.w - mx);
  float s = v.x + v.y + v.z + v.w;
  s = waveSum(s);
  __syncthreads();
  if (lane == 0) sb[wid] = s;
  __syncthreads();
  if (threadIdx.x == 0) broad = sb[0] + sb[1] + sb[2] + sb[3];
  __syncthreads();
  float inv = 1.0f / broad;
  uint2 o;
  o.x = (unsigned)f2bf(v.x * inv) | ((unsigned)f2bf(v.y * inv) << 16);
  o.y = (unsigned)f2bf(v.z * inv) | ((unsigned)f2bf(v.w * inv) << 16);
  ((uint2*)(A + (size_t)blockIdx.x * NT))[threadIdx.x] = o;
}

// ---------------- BN stats, token-major z [8192][512] bf16: 2-stage ----------------
__global__ __launch_bounds__(256) void bnstats_tm_part(
    const u16* __restrict__ Z, float* __restrict__ pS, float* __restrict__ pS2) {
  int blk = blockIdx.x;
  int c2 = threadIdx.x;
  float s0 = 0, s1 = 0, q0 = 0, q1 = 0;
  const u16* base = Z + (size_t)blk * 32 * CC;
#pragma unroll 4
  for (int r = 0; r < 32; r++) {
    unsigned u = *(const unsigned*)(base + (size_t)r * CC + c2 * 2);
    float a = bf2f((u16)u), b = bf2f((u16)(u >> 16));
    s0 += a; q0 += a * a; s1 += b; q1 += b * b;
  }
  pS[(size_t)(c2 * 2) * 256 + blk] = s0;
  pS[(size_t)(c2 * 2 + 1) * 256 + blk] = s1;
  pS2[(size_t)(c2 * 2) * 256 + blk] = q0;
  pS2[(size_t)(c2 * 2 + 1) * 256 + blk] = q1;
}
__global__ __launch_bounds__(256) void bnstats_tm_reduce(
    const float* __restrict__ pS, const float* __restrict__ pS2,
    const float* __restrict__ g, const float* __restrict__ bet,
    float* __restrict__ scale, float* __restrict__ shift) {
  int c = blockIdx.x;
  float s = pS[(size_t)c * 256 + threadIdx.x];
  float s2 = pS2[(size_t)c * 256 + threadIdx.x];
  s = waveSum(s); s2 = waveSum(s2);
  __shared__ float sb[8];
  int lane = threadIdx.x & 63, wid = threadIdx.x >> 6;
  if (lane == 0) { sb[wid] = s; sb[wid + 4] = s2; }
  __syncthreads();
  if (threadIdx.x == 0) {
    float S = sb[0] + sb[1] + sb[2] + sb[3];
    float S2 = sb[4] + sb[5] + sb[6] + sb[7];
    const float invn = 1.0f / (BB * NT);
    float mean = S * invn;
    float var = S2 * invn - mean * mean;
    float inv = rsqrtf(var + BN_EPS);
    float sc = g[c] * inv;
    scale[c] = sc;
    shift[c] = bet[c] - mean * sc;
  }
}

// ---------------- BN stats, channel-major z [512][8192] bf16: 1-stage ----------------
__global__ __launch_bounds__(256) void bnstats_cm(
    const u16* __restrict__ Z, const float* __restrict__ g, const float* __restrict__ bet,
    float* __restrict__ scale, float* __restrict__ shift) {
  int c = blockIdx.x;
  const uint2* row = (const uint2*)(Z + (size_t)c * (BB * NT));
  float s = 0, s2 = 0;
#pragma unroll
  for (int it = 0; it < 8; it++) {
    uint2 u = row[threadIdx.x + it * 256];
    float a = bf2f((u16)u.x), b = bf2f((u16)(u.x >> 16));
    float d = bf2f((u16)u.y), e = bf2f((u16)(u.y >> 16));
    s += a + b + d + e;
    s2 += a * a + b * b + d * d + e * e;
  }
  s = waveSum(s); s2 = waveSum(s2);
  __shared__ float sb[8];
  int lane = threadIdx.x & 63, wid = threadIdx.x >> 6;
  if (lane == 0) { sb[wid] = s; sb[wid + 4] = s2; }
  __syncthreads();
  if (threadIdx.x == 0) {
    float S = sb[0] + sb[1] + sb[2] + sb[3];
    float S2 = sb[4] + sb[5] + sb[6] + sb[7];
    const float invn = 1.0f / (BB * NT);
    float mean = S * invn;
    float var = S2 * invn - mean * mean;
    float inv = rsqrtf(var + BN_EPS);
    float sc = g[c] * inv;
    scale[c] = sc;
    shift[c] = bet[c] - mean * sc;
  }
}

// ---------------- BN apply + relu, token-major bf16 -> bf16 ----------------
__global__ __launch_bounds__(256) void bn_apply_kernel(
    const u16* __restrict__ Z, u16* __restrict__ Zo,
    const float* __restrict__ scale, const float* __restrict__ shift) {
  size_t e4 = (size_t)blockIdx.x * 256 + threadIdx.x;
  int c = (int)(e4 & 127) * 4;
  uint2 u = ((const uint2*)Z)[e4];
  float a = bf2f((u16)u.x), b = bf2f((u16)(u.x >> 16));
  float d = bf2f((u16)u.y), e = bf2f((u16)(u.y >> 16));
  a = fmaxf(fmaf(a, scale[c], shift[c]), 0.f);
  b = fmaxf(fmaf(b, scale[c + 1], shift[c + 1]), 0.f);
  d = fmaxf(fmaf(d, scale[c + 2], shift[c + 2]), 0.f);
  e = fmaxf(fmaf(e, scale[c + 3], shift[c + 3]), 0.f);
  uint2 o;
  o.x = (unsigned)f2bf(a) | ((unsigned)f2bf(b) << 16);
  o.y = (unsigned)f2bf(d) | ((unsigned)f2bf(e) << 16);
  ((uint2*)Zo)[e4] = o;
}

// ---------------- BN final: z2 cm bf16 + x fp32 -> out fp32 ----------------
__global__ __launch_bounds__(256) void bn_final_kernel(
    const u16* __restrict__ Z2, const float* __restrict__ X,
    const float* __restrict__ scale, const float* __restrict__ shift,
    float* __restrict__ Out) {
  size_t e = (size_t)blockIdx.x * 256 + threadIdx.x;
  int c = (int)(e >> 11);
  int r = (int)(e & 2047);
  int b = r >> 8;
  uint2 u = ((const uint2*)(Z2 + (size_t)c * (BB * NT)))[r];
  float a0 = bf2f((u16)u.x), a1 = bf2f((u16)(u.x >> 16));
  float a2 = bf2f((u16)u.y), a3 = bf2f((u16)(u.y >> 16));
  float sc = scale[c], sh = shift[c];
  size_t xi = ((size_t)b * CC + c) * 256 + (r & 255);
  float4 xv = ((const float4*)X)[xi];
  float4 o;
  o.x = fmaxf(fmaf(a0, sc, sh) + xv.x, 0.f);
  o.y = fmaxf(fmaf(a1, sc, sh) + xv.y, 0.f);
  o.z = fmaxf(fmaf(a2, sc, sh) + xv.z, 0.f);
  o.w = fmaxf(fmaf(a3, sc, sh) + xv.w, 0.f);
  ((float4*)Out)[xi] = o;
}

extern "C" void kernel_launch(void* const* d_in, const int* in_sizes, int n_in,
                              void* d_out, int out_size, void* d_ws, size_t ws_size,
                              hipStream_t stream) {
  (void)in_sizes; (void)n_in; (void)out_size; (void)ws_size;
  const float* x    = (const float*)d_in[0];
  const float* y    = (const float*)d_in[1];
  const float* xh   = (const float*)d_in[2];
  const float* yh   = (const float*)d_in[3];
  const float* qW   = (const float*)d_in[4];
  const float* qb   = (const float*)d_in[5];
  const float* kW   = (const float*)d_in[6];
  const float* kb   = (const float*)d_in[7];
  const float* v1W  = (const float*)d_in[8];
  const float* v1b  = (const float*)d_in[9];
  const float* v2W  = (const float*)d_in[10];
  const float* v2b  = (const float*)d_in[11];
  const float* hw1  = (const float*)d_in[12];
  const float* hw2  = (const float*)d_in[13];
  const float* g1W1 = (const float*)d_in[14];
  const float* g1b1 = (const float*)d_in[15];
  const float* g1W2 = (const float*)d_in[16];
  const float* g1b2 = (const float*)d_in[17];
  const float* g2W1 = (const float*)d_in[18];
  const float* g2b1 = (const float*)d_in[19];
  const float* g2W2 = (const float*)d_in[20];
  const float* g2b2 = (const float*)d_in[21];
  const float* rW1  = (const float*)d_in[22];
  // d_in[23] = rb1 dropped (BN absorbs constant bias)
  const float* bn1g = (const float*)d_in[24];
  const float* bn1b = (const float*)d_in[25];
  const float* rW2  = (const float*)d_in[26];
  // d_in[27] = rb2 dropped
  const float* bn2g = (const float*)d_in[28];
  const float* bn2b = (const float*)d_in[29];
  float* out = (float*)d_out;

  // ---- workspace layout (floats then u16) ----
  float* ws  = (float*)d_ws;
  float* lm  = ws;                 // 81,920
  float* gam = ws + 81920;         // 16
  float* scA = ws + 81936;         // 512
  float* shA = ws + 82448;         // 512
  float* pS  = ws + 82960;         // 131,072
  float* pS2 = ws + 214032;        // 131,072
  float* S   = ws + 345104;        // 8,388,608 fp32 scores
  u16* U     = (u16*)(ws + 8733712);
  u16* Wqh = U;                    // 32,768
  u16* Wql = U + 32768;
  u16* Wkh = U + 65536;
  u16* Wkl = U + 98304;
  u16* Wv1 = U + 131072;           // 262,144 each
  u16* Wv2 = U + 393216;
  u16* Wr1 = U + 655360;
  u16* Wr2 = U + 917504;
  u16* xth = U + 1179648;          // 4,194,304 each
  u16* yth = xth + 4194304;
  u16* xtl = yth + 4194304;
  u16* ytl = xtl + 4194304;
  u16* q_h = ytl + 4194304;        // 524,288 each
  u16* q_l = q_h + 524288;
  u16* k_h = q_l + 524288;
  u16* k_l = k_h + 524288;
  u16* v1  = k_l + 524288;         // 4,194,304 each
  u16* v2  = v1 + 4194304;
  u16* attn = v2 + 4194304;        // 8,388,608
  // overlays (stream-serialized lifetimes):
  u16* attnT = xtl;                // xtl+ytl dead after q/k-proj; 8,388,608 contiguous
  u16* o1t = xth;                  // dead after v1/q proj
  u16* o2t = yth;
  u16* z0  = v1;                   // dead after out1
  u16* z1  = v2;                   // dead after out2
  u16* z2  = attn;                 // dead after out1 (out2 uses attnT)

  const long long sX = (long long)CC * NT;

  // 1) weight conversions + hidden means + gamma
  WcvtArgs wa;
  wa.src[0] = v1W; wa.src[1] = v2W; wa.src[2] = rW1; wa.src[3] = rW2;
  int pref[5] = {0, 256, 512, 768, 1024};
  for (int i = 0; i < 5; i++) wa.nblk[i] = pref[i];
  wcvt_kernel<<<1024, 256, 0, stream>>>(wa, Wv1);
  wcvt_split_kernel<<<64, 256, 0, stream>>>(qW, kW, Wqh, Wql, Wkh, Wkl);
  hidden_mean_kernel<<<2 * LL * BB * CC, 256, 0, stream>>>(xh, yh, lm);
  gamma_kernel<<<16, 256, 0, stream>>>(lm, hw1, hw2, g1W1, g1b1, g1W2, g1b2,
                                       g2W1, g2b1, g2W2, g2b2, gam);

  // 2) x,y -> token-major split bf16
  transpose_xy_kernel<<<dim3(16, 8, 16), 256, 0, stream>>>(x, y, xth, xtl, yth, ytl);

  // 3) v projections (hi-only inputs; linear path, bf16-safe)
  gemm_bf16<128><<<dim3(64, 4, 1), 256, 0, stream>>>(Wv1, 0, CC, xth, 0, CC, v1, 0, BB * NT,
                                                     CC, 0, v1b, nullptr, nullptr);
  gemm_bf16<128><<<dim3(64, 4, 1), 256, 0, stream>>>(Wv2, 0, CC, yth, 0, CC, v2, 0, BB * NT,
                                                     CC, 0, v2b, nullptr, nullptr);
  // q/k projections: split inputs -> split outputs (~fp32 accuracy)
  gemm_split<<<dim3(1, 64, 1), 256, 0, stream>>>(xth, xtl, 0, CC, Wqh, Wql, 0, CC,
                                                 nullptr, q_h, q_l, 0, DQK, CC, qb);
  gemm_split<<<dim3(1, 64, 1), 256, 0, stream>>>(yth, ytl, 0, CC, Wkh, Wkl, 0, CC,
                                                 nullptr, k_h, k_l, 0, DQK, CC, kb);

  // 4) scores (split inputs -> fp32), softmax -> bf16 attn, transpose
  gemm_split<<<dim3(16, 8, 8), 256, 0, stream>>>(q_h, q_l, (long long)NT * DQK, DQK,
                                                 k_h, k_l, (long long)NT * DQK, DQK,
                                                 S, nullptr, nullptr,
                                                 (long long)NT * NT, NT, DQK, nullptr);
  softmax_bf_kernel<<<BB * NT, 256, 0, stream>>>(S, attn);
  transpose_attn_kernel<<<dim3(16, 16, 8), 256, 0, stream>>>(attn, attnT);

  // 5) attention-apply
  gemm_bf16<128><<<dim3(4, 8, 8), 256, 0, stream>>>(attn, (long long)NT * NT, NT,
                                                    v1, NT, BB * NT,
                                                    o1t, (long long)NT * CC, CC,
                                                    NT, 0, nullptr, nullptr, gam);
  gemm_bf16<128><<<dim3(4, 8, 8), 256, 0, stream>>>(attnT, (long long)NT * NT, NT,
                                                    v2, NT, BB * NT,
                                                    o2t, (long long)NT * CC, CC,
                                                    NT, 0, nullptr, nullptr, gam + BB);

  // 6) residual chain 1
  gemm_bf16<128><<<dim3(4, 64, 1), 256, 0, stream>>>(o1t, 0, CC, Wr1, 0, CC, z0, 0, CC,
                                                     CC, 0, nullptr, nullptr, nullptr);
  bnstats_tm_part<<<256, 256, 0, stream>>>(z0, pS, pS2);
  bnstats_tm_reduce<<<512, 256, 0, stream>>>(pS, pS2, bn1g, bn1b, scA, shA);
  bn_apply_kernel<<<4096, 256, 0, stream>>>(z0, z1, scA, shA);
  gemm_bf16<128><<<dim3(64, 4, 1), 256, 0, stream>>>(Wr2, 0, CC, z1, 0, CC, z2, 0, BB * NT,
                                                     CC, 0, nullptr, nullptr, nullptr);
  bnstats_cm<<<512, 256, 0, stream>>>(z2, bn2g, bn2b, scA, shA);
  bn_final_kernel<<<4096, 256, 0, stream>>>(z2, x, scA, shA, out);

  // 7) residual chain 2
  gemm_bf16<128><<<dim3(4, 64, 1), 256, 0, stream>>>(o2t, 0, CC, Wr1, 0, CC, z0, 0, CC,
                                                     CC, 0, nullptr, nullptr, nullptr);
  bnstats_tm_part<<<256, 256, 0, stream>>>(z0, pS, pS2);
  bnstats_tm_reduce<<<512, 256, 0, stream>>>(pS, pS2, bn1g, bn1b, scA, shA);
  bn_apply_kernel<<<4096, 256, 0, stream>>>(z0, z1, scA, shA);
  gemm_bf16<128><<<dim3(64, 4, 1), 256, 0, stream>>>(Wr2, 0, CC, z1, 0, CC, z2, 0, BB * NT,
                                                     CC, 0, nullptr, nullptr, nullptr);
  bnstats_cm<<<512, 256, 0, stream>>>(z2, bn2g, bn2b, scA, shA);
  bn_final_kernel<<<4096, 256, 0, stream>>>(z2, y, scA, shA, out + (size_t)BB * sX);
}

// Round 4
// 320.052 us; speedup vs baseline: 2.7704x; 1.4070x over previous
//
#include <hip/hip_runtime.h>

#define BB 8
#define CC 512
#define NT 1024
#define LL 10
#define DQK 64
#define BN_EPS 1e-5f

using u16 = unsigned short;
typedef __attribute__((ext_vector_type(8))) short short8;
typedef __attribute__((ext_vector_type(4))) float f32x4;

// ---------------- helpers ----------------
__device__ __forceinline__ float waveSum(float v) {
#pragma unroll
  for (int o = 32; o; o >>= 1) v += __shfl_down(v, o, 64);
  return v;
}
__device__ __forceinline__ float waveMax(float v) {
#pragma unroll
  for (int o = 32; o; o >>= 1) v = fmaxf(v, __shfl_down(v, o, 64));
  return v;
}
__device__ __forceinline__ u16 f2bf(float f) {
  unsigned u = __float_as_uint(f);
  u += 0x7FFFu + ((u >> 16) & 1u);
  return (u16)(u >> 16);
}
__device__ __forceinline__ float bf2f(u16 h) {
  return __uint_as_float(((unsigned)h) << 16);
}
// async global->LDS, 16B/lane; LDS dest must be wave-uniform base + lane*16
__device__ __forceinline__ void g2l16(const u16* g, void* l) {
  __builtin_amdgcn_global_load_lds(
      (const __attribute__((address_space(1))) unsigned int*)g,
      (__attribute__((address_space(3))) unsigned int*)l, 16, 0, 0);
}

// ---------------- hidden means: wave-per-4-rows, no LDS ----------------
// grid 5120 x 256: block covers 16 rows of 1024 floats; lm[row] = mean
__global__ __launch_bounds__(256) void hidden_mean_kernel(
    const float* __restrict__ xh, const float* __restrict__ yh, float* __restrict__ lm) {
  const int LBC = LL * BB * CC;
  int wid = blockIdx.x * 4 + (threadIdx.x >> 6);
  int lane = threadIdx.x & 63;
  int row0 = wid * 4;
  const float* src = xh;
  int r0 = row0;
  if (row0 >= LBC) { src = yh; r0 = row0 - LBC; }
  const float4* p = (const float4*)(src + (size_t)r0 * NT);
  float s[4];
#pragma unroll
  for (int r = 0; r < 4; r++) {
    float4 a = p[r * 256 + lane];
    float4 b = p[r * 256 + 64 + lane];
    float4 c = p[r * 256 + 128 + lane];
    float4 d = p[r * 256 + 192 + lane];
    s[r] = ((a.x + a.y) + (a.z + a.w)) + ((b.x + b.y) + (b.z + b.w)) +
           ((c.x + c.y) + (c.z + c.w)) + ((d.x + d.y) + (d.z + d.w));
  }
#pragma unroll
  for (int r = 0; r < 4; r++) s[r] = waveSum(s[r]);
  if (lane == 0) {
    float4 o = {s[0] * (1.0f / NT), s[1] * (1.0f / NT),
                s[2] * (1.0f / NT), s[3] * (1.0f / NT)};
    *(float4*)&lm[row0] = o;
  }
}

// ---------------- gamma scalars ----------------
__global__ __launch_bounds__(256) void gamma_kernel(
    const float* __restrict__ lm,
    const float* __restrict__ hw1, const float* __restrict__ hw2,
    const float* __restrict__ g1W1, const float* __restrict__ g1b1,
    const float* __restrict__ g1W2, const float* __restrict__ g1b2,
    const float* __restrict__ g2W1, const float* __restrict__ g2b1,
    const float* __restrict__ g2W2, const float* __restrict__ g2b2,
    float* __restrict__ gamma) {
  int which = blockIdx.x >> 3;
  int b = blockIdx.x & 7;
  const float* hw = which ? hw2 : hw1;
  const float* W1 = which ? g2W1 : g1W1;
  const float* b1 = which ? g2b1 : g1b1;
  const float* W2 = which ? g2W2 : g1W2;
  const float* b2 = which ? g2b2 : g1b2;
  __shared__ float sxhw[CC];
  __shared__ float wsm[LL];
  if (threadIdx.x == 0) {
    float mx = -1e30f;
    for (int l = 0; l < LL; l++) mx = fmaxf(mx, hw[l]);
    float den = 0.f, e[LL];
    for (int l = 0; l < LL; l++) { e[l] = __expf(hw[l] - mx); den += e[l]; }
    for (int l = 0; l < LL; l++) wsm[l] = e[l] / den;
  }
  __syncthreads();
  const float* lmb = lm + (size_t)which * LL * BB * CC + b * CC;
  for (int c = threadIdx.x; c < CC; c += blockDim.x) {
    float a = 0.f;
    for (int l = 0; l < LL; l++) a += wsm[l] * lmb[l * BB * CC + c];
    sxhw[c] = a;
  }
  __syncthreads();
  float contrib = 0.f;
  if (threadIdx.x < 64) {
    int d = threadIdx.x;
    float a = b1[d];
    const float* wr = W1 + d * CC;
    for (int c = 0; c < CC; c++) a = fmaf(wr[c], sxhw[c], a);
    contrib = W2[d] * fmaxf(a, 0.f);
  }
  contrib = waveSum(contrib);
  if (threadIdx.x == 0) gamma[which * BB + b] = contrib + b2[0];
}

// ---------------- weights fp32 -> bf16 (hi only), 4 segments ----------------
struct WcvtArgs {
  const float* src[4];
  int nblk[5];
};
__global__ __launch_bounds__(256) void wcvt_kernel(WcvtArgs a, u16* __restrict__ dst) {
  int blk = blockIdx.x;
  int seg = 0;
  while (blk >= a.nblk[seg + 1]) seg++;
  int rel = blk - a.nblk[seg];
  const float4* s4 = (const float4*)a.src[seg];
  float4 v = s4[(size_t)rel * 256 + threadIdx.x];
  uint2 o;
  o.x = (unsigned)f2bf(v.x) | ((unsigned)f2bf(v.y) << 16);
  o.y = (unsigned)f2bf(v.z) | ((unsigned)f2bf(v.w) << 16);
  ((uint2*)dst)[(size_t)blk * 256 + threadIdx.x] = o;
}

// ---------------- qW/kW fp32 -> split (hi, lo) bf16; pack biases ----------------
__global__ __launch_bounds__(256) void wcvt_split_kernel(
    const float* __restrict__ qW, const float* __restrict__ kW,
    u16* __restrict__ qh, u16* __restrict__ ql,
    u16* __restrict__ kh, u16* __restrict__ kl,
    const float* __restrict__ qb, const float* __restrict__ kb,
    const float* __restrict__ v1b, const float* __restrict__ v2b,
    float* __restrict__ qkb, float* __restrict__ vb) {
  int blk = blockIdx.x;  // 64 blocks of 1024 elems; 0..31 qW, 32..63 kW
  if (blk == 0) {
    int t = threadIdx.x;
    if (t < 64) qkb[t] = qb[t];
    else if (t < 128) qkb[t] = kb[t - 64];
    vb[t] = v1b[t]; vb[t + 256] = v1b[t + 256];
    vb[t + 512] = v2b[t]; vb[t + 768] = v2b[t + 256];
  }
  const float* src = (blk < 32) ? qW : kW;
  u16* dh = (blk < 32) ? qh : kh;
  u16* dl = (blk < 32) ? ql : kl;
  int rel = blk & 31;
  float4 v = ((const float4*)src)[(size_t)rel * 256 + threadIdx.x];
  u16 h0 = f2bf(v.x), h1 = f2bf(v.y), h2 = f2bf(v.z), h3 = f2bf(v.w);
  u16 l0 = f2bf(v.x - bf2f(h0)), l1 = f2bf(v.y - bf2f(h1));
  u16 l2 = f2bf(v.z - bf2f(h2)), l3 = f2bf(v.w - bf2f(h3));
  uint2 oh, ol;
  oh.x = (unsigned)h0 | ((unsigned)h1 << 16); oh.y = (unsigned)h2 | ((unsigned)h3 << 16);
  ol.x = (unsigned)l0 | ((unsigned)l1 << 16); ol.y = (unsigned)l2 | ((unsigned)l3 << 16);
  ((uint2*)dh)[(size_t)rel * 256 + threadIdx.x] = oh;
  ((uint2*)dl)[(size_t)rel * 256 + threadIdx.x] = ol;
}

// ---------------- x/y [B][C][N] fp32 -> token-major split bf16 ----------------
__global__ __launch_bounds__(256) void transpose_xy_kernel(
    const float* __restrict__ x, const float* __restrict__ y,
    u16* __restrict__ xth, u16* __restrict__ xtl,
    u16* __restrict__ yth, u16* __restrict__ ytl) {
  __shared__ float t[64][65];
  int z = blockIdx.z;
  const float* src = (z < 8) ? x : y;
  u16* dh = (z < 8) ? xth : yth;
  u16* dl = (z < 8) ? xtl : ytl;
  int b = z & 7;
  int n0 = blockIdx.x * 64, c0 = blockIdx.y * 64;
  int tc = threadIdx.x & 63, tr = threadIdx.x >> 6;
  const float* S = src + ((size_t)b * CC + c0) * NT + n0;
#pragma unroll
  for (int r = 0; r < 16; r++) {
    int c = tr + r * 4;
    t[c][tc] = S[(size_t)c * NT + tc];
  }
  __syncthreads();
  size_t base = ((size_t)b * NT + n0) * CC + c0;
#pragma unroll
  for (int r = 0; r < 16; r++) {
    int n = tr + r * 4;
    float v = t[tc][n];
    u16 h = f2bf(v);
    dh[base + (size_t)n * CC + tc] = h;
    dl[base + (size_t)n * CC + tc] = f2bf(v - bf2f(h));
  }
}

// ---------------- attn [b][n][m] bf16 -> attnT [b][m][n] bf16 ----------------
__global__ __launch_bounds__(256) void transpose_attn_kernel(
    const u16* __restrict__ attn, u16* __restrict__ attnT) {
  __shared__ u16 t[64][66];
  int b = blockIdx.z;
  int n0 = blockIdx.y * 64, m0 = blockIdx.x * 64;
  int tc = threadIdx.x & 63, tr = threadIdx.x >> 6;
  const u16* S = attn + ((size_t)b * NT + n0) * NT + m0;
#pragma unroll
  for (int r = 0; r < 16; r++) {
    int nr = tr + r * 4;
    t[nr][tc] = S[(size_t)nr * NT + tc];
  }
  __syncthreads();
  u16* D = attnT + ((size_t)b * NT + m0) * NT + n0;
#pragma unroll
  for (int r = 0; r < 16; r++) {
    int mr = tr + r * 4;
    D[(size_t)mr * NT + tc] = t[tc][mr];
  }
}

// ---------------- bf16 MFMA GEMM: Out[i][j] = (sum_k A[i][k]*B[j][k] + biases)*scale ----
// A offset: bz*sA. B offset: (bz&7)*sB + (bz>>3)*sB2. C offset: bz*sC.
// bias_row indexed by row with per-z stride brs; scale indexed by bz.
template <int BN>
__global__ __launch_bounds__(256) void gemm_bf16(
    const u16* __restrict__ A, long long sA, int lda,
    const u16* __restrict__ B, long long sB, long long sB2, int ldb,
    void* __restrict__ C, long long sC, int ldc,
    int K, int storef32,
    const float* __restrict__ bias_row, int brs,
    const float* __restrict__ scale) {
  constexpr int BM = 128, BK = 32;
  constexpr int WN = (BN == 128) ? 2 : 1;
  constexpr int WM = 4 / WN;
  constexpr int FM = BM / (WM * 16);
  constexpr int FN = BN / (WN * 16);
  __shared__ u16 As[BM * BK];
  __shared__ u16 Bs[BN * BK];
  const int bz = blockIdx.z;
  const int i0 = blockIdx.y * BM;
  const int j0 = blockIdx.x * BN;
  const u16* Ab = A + (size_t)bz * sA + (size_t)i0 * lda;
  const u16* Bb = B + (size_t)(bz & 7) * sB + (size_t)(bz >> 3) * sB2 + (size_t)j0 * ldb;
  const int tid = threadIdx.x;
  const int lane = tid & 63;
  const int wave = tid >> 6;
  const int wr = wave / WN, wc = wave % WN;
  const int fr = lane & 15;
  const int kg = lane >> 4;
  const int arow = tid >> 2;
  const int aq = tid & 3;

  f32x4 acc[FM][FN] = {};

  for (int k0 = 0; k0 < K; k0 += BK) {
#pragma unroll
    for (int c = 0; c < (BM * BK * 2) / 4096; c++)
      g2l16(Ab + (size_t)(arow + c * 64) * lda + k0 + aq * 8,
            (char*)As + c * 4096 + tid * 16);
#pragma unroll
    for (int c = 0; c < (BN * BK * 2) / 4096; c++)
      g2l16(Bb + (size_t)(arow + c * 64) * ldb + k0 + aq * 8,
            (char*)Bs + c * 4096 + tid * 16);
    __syncthreads();
    short8 fa[FM], fb[FN];
#pragma unroll
    for (int i = 0; i < FM; i++)
      fa[i] = *(const short8*)&As[(wr * FM * 16 + i * 16 + fr) * BK + kg * 8];
#pragma unroll
    for (int j = 0; j < FN; j++)
      fb[j] = *(const short8*)&Bs[(wc * FN * 16 + j * 16 + fr) * BK + kg * 8];
#pragma unroll
    for (int i = 0; i < FM; i++)
#pragma unroll
      for (int j = 0; j < FN; j++)
        acc[i][j] = __builtin_amdgcn_mfma_f32_16x16x32_bf16(fa[i], fb[j], acc[i][j], 0, 0, 0);
    __syncthreads();
  }

  const float scl = scale ? scale[bz] : 1.0f;
  const float* brow = bias_row ? bias_row + (size_t)bz * brs : nullptr;
  float* Cf = (float*)C + (size_t)bz * sC;
  u16* Ch = (u16*)C + (size_t)bz * sC;
#pragma unroll
  for (int i = 0; i < FM; i++) {
#pragma unroll
    for (int j = 0; j < FN; j++) {
      int col = j0 + wc * FN * 16 + j * 16 + fr;
#pragma unroll
      for (int r = 0; r < 4; r++) {
        int row = i0 + wr * FM * 16 + i * 16 + kg * 4 + r;
        float rb = brow ? brow[row] : 0.0f;
        float v = (acc[i][j][r] + rb) * scl;
        if (storef32) Cf[(size_t)row * ldc + col] = v;
        else Ch[(size_t)row * ldc + col] = f2bf(v);
      }
    }
  }
}

// ---------------- split-bf16 GEMM (~fp32 accuracy): Out = A*B^T, A,B = hi+lo ----------------
// BM=128, BN=64, 4 waves along M. Out: fp32 (Cf) or split bf16 pair (Ch,Cl).
__global__ __launch_bounds__(256) void gemm_split(
    const u16* __restrict__ Ah_, const u16* __restrict__ Al_, long long sA, int lda,
    const u16* __restrict__ Bh_, const u16* __restrict__ Bl_, long long sB, int ldb,
    float* __restrict__ Cf, u16* __restrict__ Ch, u16* __restrict__ Cl,
    long long sC, int ldc, int K, const float* __restrict__ bias_col, int bcs) {
  constexpr int BM = 128, BN = 64, BK = 32;
  constexpr int FM = 2, FN = 4;
  __shared__ u16 Ahs[BM * BK];
  __shared__ u16 Als[BM * BK];
  __shared__ u16 Bhs[BN * BK];
  __shared__ u16 Bls[BN * BK];
  const int bz = blockIdx.z;
  const int i0 = blockIdx.y * BM;
  const int j0 = blockIdx.x * BN;
  const u16* Abh = Ah_ + (size_t)bz * sA + (size_t)i0 * lda;
  const u16* Abl = Al_ + (size_t)bz * sA + (size_t)i0 * lda;
  const u16* Bbh = Bh_ + (size_t)bz * sB + (size_t)j0 * ldb;
  const u16* Bbl = Bl_ + (size_t)bz * sB + (size_t)j0 * ldb;
  const int tid = threadIdx.x;
  const int lane = tid & 63;
  const int wr = tid >> 6;
  const int fr = lane & 15;
  const int kg = lane >> 4;
  const int arow = tid >> 2;
  const int aq = tid & 3;

  f32x4 acc[FM][FN] = {};

  for (int k0 = 0; k0 < K; k0 += BK) {
#pragma unroll
    for (int c = 0; c < 2; c++) {
      g2l16(Abh + (size_t)(arow + c * 64) * lda + k0 + aq * 8,
            (char*)Ahs + c * 4096 + tid * 16);
      g2l16(Abl + (size_t)(arow + c * 64) * lda + k0 + aq * 8,
            (char*)Als + c * 4096 + tid * 16);
    }
    g2l16(Bbh + (size_t)arow * ldb + k0 + aq * 8, (char*)Bhs + tid * 16);
    g2l16(Bbl + (size_t)arow * ldb + k0 + aq * 8, (char*)Bls + tid * 16);
    __syncthreads();
    short8 fah[FM], fal[FM], fbh[FN], fbl[FN];
#pragma unroll
    for (int i = 0; i < FM; i++) {
      fah[i] = *(const short8*)&Ahs[(wr * 32 + i * 16 + fr) * BK + kg * 8];
      fal[i] = *(const short8*)&Als[(wr * 32 + i * 16 + fr) * BK + kg * 8];
    }
#pragma unroll
    for (int j = 0; j < FN; j++) {
      fbh[j] = *(const short8*)&Bhs[(j * 16 + fr) * BK + kg * 8];
      fbl[j] = *(const short8*)&Bls[(j * 16 + fr) * BK + kg * 8];
    }
#pragma unroll
    for (int i = 0; i < FM; i++)
#pragma unroll
      for (int j = 0; j < FN; j++) {
        acc[i][j] = __builtin_amdgcn_mfma_f32_16x16x32_bf16(fah[i], fbh[j], acc[i][j], 0, 0, 0);
        acc[i][j] = __builtin_amdgcn_mfma_f32_16x16x32_bf16(fah[i], fbl[j], acc[i][j], 0, 0, 0);
        acc[i][j] = __builtin_amdgcn_mfma_f32_16x16x32_bf16(fal[i], fbh[j], acc[i][j], 0, 0, 0);
      }
    __syncthreads();
  }

  const float* bcol = bias_col ? bias_col + (size_t)bz * bcs : nullptr;
  float* Cfb = Cf ? Cf + (size_t)bz * sC : nullptr;
  u16* Chb = Ch ? Ch + (size_t)bz * sC : nullptr;
  u16* Clb = Cl ? Cl + (size_t)bz * sC : nullptr;
#pragma unroll
  for (int i = 0; i < FM; i++) {
#pragma unroll
    for (int j = 0; j < FN; j++) {
      int col = j0 + j * 16 + fr;
      float cb = bcol ? bcol[col] : 0.0f;
#pragma unroll
      for (int r = 0; r < 4; r++) {
        int row = i0 + wr * 32 + i * 16 + kg * 4 + r;
        float v = acc[i][j][r] + cb;
        if (Cfb) {
          Cfb[(size_t)row * ldc + col] = v;
        } else {
          u16 h = f2bf(v);
          Chb[(size_t)row * ldc + col] = h;
          Clb[(size_t)row * ldc + col] = f2bf(v - bf2f(h));
        }
      }
    }
  }
}

// ---------------- softmax: S fp32 row -> attn bf16 row ----------------
__global__ __launch_bounds__(256) void softmax_bf_kernel(
    const float* __restrict__ S, u16* __restrict__ A) {
  const float4* row = (const float4*)(S + (size_t)blockIdx.x * NT);
  float4 v = row[threadIdx.x];
  __shared__ float sb[4];
  __shared__ float broad;
  int lane = threadIdx.x & 63, wid = threadIdx.x >> 6;
  float mx = fmaxf(fmaxf(v.x, v.y), fmaxf(v.z, v.w));
  mx = waveMax(mx);
  if (lane == 0) sb[wid] = mx;
  __syncthreads();
  if (threadIdx.x == 0) broad = fmaxf(fmaxf(sb[0], sb[1]), fmaxf(sb[2], sb[3]));
  __syncthreads();
  mx = broad;
  v.x = __expf(v.x - mx); v.y = __expf(v.y - mx);
  v.z = __expf(v.z - mx); v.w = __expf(v.w - mx);
  float s = v.x + v.y + v.z + v.w;
  s = waveSum(s);
  __syncthreads();
  if (lane == 0) sb[wid] = s;
  __syncthreads();
  if (threadIdx.x == 0) broad = sb[0] + sb[1] + sb[2] + sb[3];
  __syncthreads();
  float inv = 1.0f / broad;
  uint2 o;
  o.x = (unsigned)f2bf(v.x * inv) | ((unsigned)f2bf(v.y * inv) << 16);
  o.y = (unsigned)f2bf(v.z * inv) | ((unsigned)f2bf(v.w * inv) << 16);
  ((uint2*)(A + (size_t)blockIdx.x * NT))[threadIdx.x] = o;
}

// ---------------- BN stats, token-major z0 [2][8192][512] bf16, 2-stage (merged chains) ----
__global__ __launch_bounds__(256) void bnstats_tm_part(
    const u16* __restrict__ Z, float* __restrict__ pS, float* __restrict__ pS2) {
  int blk = blockIdx.x;           // 512 blocks; 256 per chain
  int chain = blk >> 8, bl = blk & 255;
  int c2 = threadIdx.x;
  float s0 = 0, s1 = 0, q0 = 0, q1 = 0;
  const u16* base = Z + (size_t)blk * 32 * CC;
#pragma unroll 4
  for (int r = 0; r < 32; r++) {
    unsigned u = *(const unsigned*)(base + (size_t)r * CC + c2 * 2);
    float a = bf2f((u16)u), b = bf2f((u16)(u >> 16));
    s0 += a; q0 += a * a; s1 += b; q1 += b * b;
  }
  size_t co = (size_t)chain * 512;
  pS[(co + c2 * 2) * 256 + bl] = s0;
  pS[(co + c2 * 2 + 1) * 256 + bl] = s1;
  pS2[(co + c2 * 2) * 256 + bl] = q0;
  pS2[(co + c2 * 2 + 1) * 256 + bl] = q1;
}
__global__ __launch_bounds__(256) void bnstats_tm_reduce(
    const float* __restrict__ pS, const float* __restrict__ pS2,
    const float* __restrict__ g, const float* __restrict__ bet,
    float* __restrict__ scale, float* __restrict__ shift) {
  int cg = blockIdx.x;            // 1024 = [chain][c]
  int c = cg & 511;
  float s = pS[(size_t)cg * 256 + threadIdx.x];
  float s2 = pS2[(size_t)cg * 256 + threadIdx.x];
  s = waveSum(s); s2 = waveSum(s2);
  __shared__ float sb[8];
  int lane = threadIdx.x & 63, wid = threadIdx.x >> 6;
  if (lane == 0) { sb[wid] = s; sb[wid + 4] = s2; }
  __syncthreads();
  if (threadIdx.x == 0) {
    float S = sb[0] + sb[1] + sb[2] + sb[3];
    float S2 = sb[4] + sb[5] + sb[6] + sb[7];
    const float invn = 1.0f / (BB * NT);
    float mean = S * invn;
    float var = S2 * invn - mean * mean;
    float inv = rsqrtf(var + BN_EPS);
    float sc = g[c] * inv;
    scale[cg] = sc;
    shift[cg] = bet[c] - mean * sc;
  }
}

// ---------------- BN stats, channel-major z2 [2][512][8192] bf16 (merged) ----------------
__global__ __launch_bounds__(256) void bnstats_cm(
    const u16* __restrict__ Z, const float* __restrict__ g, const float* __restrict__ bet,
    float* __restrict__ scale, float* __restrict__ shift) {
  int cg = blockIdx.x;            // 1024
  int c = cg & 511;
  const uint2* row = (const uint2*)(Z + (size_t)cg * (BB * NT));
  float s = 0, s2 = 0;
#pragma unroll
  for (int it = 0; it < 8; it++) {
    uint2 u = row[threadIdx.x + it * 256];
    float a = bf2f((u16)u.x), b = bf2f((u16)(u.x >> 16));
    float d = bf2f((u16)u.y), e = bf2f((u16)(u.y >> 16));
    s += a + b + d + e;
    s2 += a * a + b * b + d * d + e * e;
  }
  s = waveSum(s); s2 = waveSum(s2);
  __shared__ float sb[8];
  int lane = threadIdx.x & 63, wid = threadIdx.x >> 6;
  if (lane == 0) { sb[wid] = s; sb[wid + 4] = s2; }
  __syncthreads();
  if (threadIdx.x == 0) {
    float S = sb[0] + sb[1] + sb[2] + sb[3];
    float S2 = sb[4] + sb[5] + sb[6] + sb[7];
    const float invn = 1.0f / (BB * NT);
    float mean = S * invn;
    float var = S2 * invn - mean * mean;
    float inv = rsqrtf(var + BN_EPS);
    float sc = g[c] * inv;
    scale[cg] = sc;
    shift[cg] = bet[c] - mean * sc;
  }
}

// ---------------- BN apply + relu, token-major [2][8192][512] bf16 (merged) ----------------
__global__ __launch_bounds__(256) void bn_apply_kernel(
    const u16* __restrict__ Z, u16* __restrict__ Zo,
    const float* __restrict__ scale, const float* __restrict__ shift) {
  size_t e4 = (size_t)blockIdx.x * 256 + threadIdx.x;  // uint2 index; 2^21 total
  int chain = (int)(e4 >> 20);
  int c = (int)(e4 & 127) * 4 + chain * 512;
  uint2 u = ((const uint2*)Z)[e4];
  float a = bf2f((u16)u.x), b = bf2f((u16)(u.x >> 16));
  float d = bf2f((u16)u.y), e = bf2f((u16)(u.y >> 16));
  a = fmaxf(fmaf(a, scale[c], shift[c]), 0.f);
  b = fmaxf(fmaf(b, scale[c + 1], shift[c + 1]), 0.f);
  d = fmaxf(fmaf(d, scale[c + 2], shift[c + 2]), 0.f);
  e = fmaxf(fmaf(e, scale[c + 3], shift[c + 3]), 0.f);
  uint2 o;
  o.x = (unsigned)f2bf(a) | ((unsigned)f2bf(b) << 16);
  o.y = (unsigned)f2bf(d) | ((unsigned)f2bf(e) << 16);
  ((uint2*)Zo)[e4] = o;
}

// ---------------- BN final: z2 [2][512][8192] + x/y fp32 -> out (merged) ----------------
__global__ __launch_bounds__(256) void bn_final_kernel(
    const u16* __restrict__ Z2, const float* __restrict__ X, const float* __restrict__ Y,
    const float* __restrict__ scale, const float* __restrict__ shift,
    float* __restrict__ Out) {
  size_t e = (size_t)blockIdx.x * 256 + threadIdx.x;  // 4-elem groups; 2^21 total
  int chain = (int)(e >> 20);
  size_t ec = e & 1048575;
  int c = (int)(ec >> 11);
  int r = (int)(ec & 2047);
  int b = r >> 8;
  uint2 u = ((const uint2*)Z2)[e];
  float a0 = bf2f((u16)u.x), a1 = bf2f((u16)(u.x >> 16));
  float a2 = bf2f((u16)u.y), a3 = bf2f((u16)(u.y >> 16));
  float sc = scale[c + chain * 512], sh = shift[c + chain * 512];
  size_t xi = ((size_t)b * CC + c) * 256 + (r & 255);
  const float* Xs = chain ? Y : X;
  float4 xv = ((const float4*)Xs)[xi];
  float4 o;
  o.x = fmaxf(fmaf(a0, sc, sh) + xv.x, 0.f);
  o.y = fmaxf(fmaf(a1, sc, sh) + xv.y, 0.f);
  o.z = fmaxf(fmaf(a2, sc, sh) + xv.z, 0.f);
  o.w = fmaxf(fmaf(a3, sc, sh) + xv.w, 0.f);
  ((float4*)(Out + (size_t)chain * 4194304))[xi] = o;
}

extern "C" void kernel_launch(void* const* d_in, const int* in_sizes, int n_in,
                              void* d_out, int out_size, void* d_ws, size_t ws_size,
                              hipStream_t stream) {
  (void)in_sizes; (void)n_in; (void)out_size; (void)ws_size;
  const float* x    = (const float*)d_in[0];
  const float* y    = (const float*)d_in[1];
  const float* xh   = (const float*)d_in[2];
  const float* yh   = (const float*)d_in[3];
  const float* qW   = (const float*)d_in[4];
  const float* qb   = (const float*)d_in[5];
  const float* kW   = (const float*)d_in[6];
  const float* kb   = (const float*)d_in[7];
  const float* v1W  = (const float*)d_in[8];
  const float* v1b  = (const float*)d_in[9];
  const float* v2W  = (const float*)d_in[10];
  const float* v2b  = (const float*)d_in[11];
  const float* hw1  = (const float*)d_in[12];
  const float* hw2  = (const float*)d_in[13];
  const float* g1W1 = (const float*)d_in[14];
  const float* g1b1 = (const float*)d_in[15];
  const float* g1W2 = (const float*)d_in[16];
  const float* g1b2 = (const float*)d_in[17];
  const float* g2W1 = (const float*)d_in[18];
  const float* g2b1 = (const float*)d_in[19];
  const float* g2W2 = (const float*)d_in[20];
  const float* g2b2 = (const float*)d_in[21];
  const float* rW1  = (const float*)d_in[22];
  // d_in[23] = rb1 dropped (BN absorbs constant bias)
  const float* bn1g = (const float*)d_in[24];
  const float* bn1b = (const float*)d_in[25];
  const float* rW2  = (const float*)d_in[26];
  // d_in[27] = rb2 dropped
  const float* bn2g = (const float*)d_in[28];
  const float* bn2b = (const float*)d_in[29];
  float* out = (float*)d_out;

  // ---- workspace layout ----
  float* ws  = (float*)d_ws;
  float* lm  = ws;                  // 81,920
  float* gam = ws + 81920;          // 16
  float* scA = ws + 81936;          // 1,024 (2 chains)
  float* shA = ws + 82960;          // 1,024
  float* qkb = ws + 83984;          // 128
  float* vb  = ws + 84112;          // 1,024
  float* pS  = ws + 85136;          // 262,144 (2 chains)
  float* pS2 = ws + 347280;         // 262,144
  float* S   = ws + 609424;         // 8,388,608 fp32 scores
  u16* U     = (u16*)(ws + 8998032);
  u16* Wqh = U;                     // 32,768 | order: Wqh,Wql,Wkh,Wkl (h/l stride 65,536)
  u16* Wql = U + 32768;
  u16* Wkh = U + 65536;
  u16* Wkl = U + 98304;
  u16* Wv1 = U + 131072;            // 262,144 each, Wv1->Wv2 contiguous
  u16* Wv2 = U + 393216;
  u16* Wr1 = U + 655360;
  u16* Wr2 = U + 917504;
  u16* xth = U + 1179648;           // 4,194,304 each; xth->yth contiguous
  u16* yth = xth + 4194304;
  u16* xtl = yth + 4194304;
  u16* ytl = xtl + 4194304;
  u16* q_h = ytl + 4194304;         // 524,288 each; q->k stride 1,048,576
  u16* q_l = q_h + 524288;
  u16* k_h = q_l + 524288;
  u16* k_l = k_h + 524288;
  u16* v1  = k_l + 524288;          // 4,194,304 each; v1->v2 contiguous
  u16* v2  = v1 + 4194304;
  u16* attn  = v2 + 4194304;        // 8,388,608
  u16* attnT = attn + 8388608;      // 8,388,608 (contiguous after attn!)
  // overlays (stream-serialized lifetimes):
  u16* o1t = xth;   // [2][8192][512] token-major outs (o2t = yth follows)
  u16* z0  = v1;    // [2][8192][512] conv1 out
  u16* z1  = xth;   // [2][8192][512] bn1-relu out
  u16* z2  = attn;  // [2][512][8192] conv2 out (cm)

  // 1) weight conversions (+ bias packs) + hidden means + gamma
  WcvtArgs wa;
  wa.src[0] = v1W; wa.src[1] = v2W; wa.src[2] = rW1; wa.src[3] = rW2;
  int pref[5] = {0, 256, 512, 768, 1024};
  for (int i = 0; i < 5; i++) wa.nblk[i] = pref[i];
  wcvt_kernel<<<1024, 256, 0, stream>>>(wa, Wv1);
  wcvt_split_kernel<<<64, 256, 0, stream>>>(qW, kW, Wqh, Wql, Wkh, Wkl,
                                            qb, kb, v1b, v2b, qkb, vb);
  hidden_mean_kernel<<<5120, 256, 0, stream>>>(xh, yh, lm);
  gamma_kernel<<<16, 256, 0, stream>>>(lm, hw1, hw2, g1W1, g1b1, g1W2, g1b2,
                                       g2W1, g2b1, g2W2, g2b2, gam);

  // 2) x,y -> token-major split bf16
  transpose_xy_kernel<<<dim3(16, 8, 16), 256, 0, stream>>>(x, y, xth, xtl, yth, ytl);

  // 3) merged v-projections (z: 0=v1 from x, 1=v2 from y)
  gemm_bf16<128><<<dim3(64, 4, 2), 256, 0, stream>>>(
      Wv1, 262144, CC, xth, 4194304, 0, CC, v1, 4194304, BB * NT, CC, 0, vb, 512, nullptr);
  // merged q/k projections (split path)
  gemm_split<<<dim3(1, 64, 2), 256, 0, stream>>>(
      xth, xtl, 4194304, CC, Wqh, Wql, 65536, CC,
      nullptr, q_h, q_l, 1048576, DQK, CC, qkb, 64);

  // 4) scores (split -> fp32), softmax -> bf16 attn, transpose -> attnT
  gemm_split<<<dim3(16, 8, 8), 256, 0, stream>>>(
      q_h, q_l, (long long)NT * DQK, DQK, k_h, k_l, (long long)NT * DQK, DQK,
      S, nullptr, nullptr, (long long)NT * NT, NT, DQK, nullptr, 0);
  softmax_bf_kernel<<<BB * NT, 256, 0, stream>>>(S, attn);
  transpose_attn_kernel<<<dim3(16, 16, 8), 256, 0, stream>>>(attn, attnT);

  // 5) merged attention-apply (z = which*8 + b; A walks attn then attnT; B picks v1/v2)
  gemm_bf16<128><<<dim3(4, 8, 16), 256, 0, stream>>>(
      attn, (long long)NT * NT, NT, v1, NT, 4194304, BB * NT,
      o1t, (long long)NT * CC, CC, NT, 0, nullptr, 0, gam);

  // 6) merged residual chains (z: 0=chain1, 1=chain2)
  gemm_bf16<128><<<dim3(4, 64, 2), 256, 0, stream>>>(
      o1t, 4194304, CC, Wr1, 0, 0, CC, z0, 4194304, CC, CC, 0, nullptr, 0, nullptr);
  bnstats_tm_part<<<512, 256, 0, stream>>>(z0, pS, pS2);
  bnstats_tm_reduce<<<1024, 256, 0, stream>>>(pS, pS2, bn1g, bn1b, scA, shA);
  bn_apply_kernel<<<8192, 256, 0, stream>>>(z0, z1, scA, shA);
  gemm_bf16<128><<<dim3(64, 4, 2), 256, 0, stream>>>(
      Wr2, 0, CC, z1, 4194304, 0, CC, z2, 4194304, BB * NT, CC, 0, nullptr, 0, nullptr);
  bnstats_cm<<<1024, 256, 0, stream>>>(z2, bn2g, bn2b, scA, shA);
  bn_final_kernel<<<8192, 256, 0, stream>>>(z2, x, y, scA, shA, out);
}